// Round 1
// 773.193 us; speedup vs baseline: 1.1577x; 1.1577x over previous
//
#include <hip/hip_runtime.h>
#include <hip/hip_bf16.h>
#include <math.h>

// Problem constants
#define TOKENS   16384        // T*Z
#define DDIM     1024
#define NEXP     64
#define PSLOT    32
#define NSLOTS   2048         // NEXP*PSLOT
#define HDIM     1024
#define LN_EPS   1e-5f
#define KSPLIT   8            // split-K factor for GEMM2 (D^T x)

typedef __bf16 b16x8 __attribute__((ext_vector_type(8)));
typedef float  f32x4 __attribute__((ext_vector_type(4)));

__device__ __forceinline__ unsigned short f2b(float f) {
    union { float f; unsigned u; } v; v.f = f;
    unsigned r = v.u + 0x7FFF + ((v.u >> 16) & 1);   // RNE
    return (unsigned short)(r >> 16);
}

__device__ __forceinline__ void load_lds16(const void* g, void* l) {
    __builtin_amdgcn_global_load_lds(
        (const __attribute__((address_space(1))) void*)g,
        (__attribute__((address_space(3))) void*)l, 16, 0, 0);
}

// ---------------------------------------------------------------------------
// 256x256 8-phase pipelined bf16 MFMA GEMM, NT layout:
//   C[M,N] = A[M,K] * B[N,K]^T (+ bias over N), split-K via gridDim.z.
// 512 threads = 8 waves (2 M x 4 N), per-wave output 128x64 (8x4 frags of
// 16x16, K-step 32). BK=64; LDS = 2 bufs x (A 256x64 + B 256x64) bf16 = 128KB.
// Schedule (derived from the verified m201 template):
//   iter = 2 K-tiles (t0 -> buf0, t1 -> buf1), 8 phases; each phase =
//   {ds_read quadrant frags | issue 1 half-tile global_load_lds | s_barrier |
//    16 MFMA (setprio 1) | s_barrier}; counted s_waitcnt vmcnt(6) ONLY at
//   phases 4 and 8 (3 half-tiles stay in flight across barriers; never drain).
// Half-tile staging targets (1 unit = 2 gload_lds instrs = 16KB):
//   ph1:A2(t1)->b1  ph2:A1(t0+2)->b0  ph3:B1(t0+2)->b0  ph4:B2(t0+2)->b0
//   ph5:A2(t0+2)->b0 ph6:A1(t1+2)->b1 ph7:B1(t1+2)->b1  ph8:B2(t1+2)->b1
// Liveness: every staged region's last LDS-read is >=1 phase earlier.
// Availability: vmcnt(6)@ph4 covers loads issued through ph1; @ph8 through
// ph5 -> each tile's 4 units land one barrier before their first read.
// LDS row permutation puts each wave's first-consumed 64 rows in the first
// staged unit: A: r' = 128*h + 64*wr + s6 <-> logical wr*128 + h*64 + s6;
//              B: r' = 128*h + 32*wc + s5 <-> logical wc*64 + h*32 + s5.
// XOR k-slot swizzle (slot s stored at s^(r'&7)) keeps ds_read_b128 2-way.
// ---------------------------------------------------------------------------
template<bool BIAS>
__global__ __launch_bounds__(512, 2) void gemm_nt_256(
    const unsigned short* __restrict__ A,   // [M, K] bf16
    const unsigned short* __restrict__ B,   // [N, K] bf16
    const float* __restrict__ bias,          // [N] or null
    float* __restrict__ C,                   // [gridDim.z][M, N]
    int M, int N, int K)
{
    __shared__ unsigned short lds[2][2][256 * 64];   // [buf][A/B][r'*64+col]
    const int tid  = threadIdx.x;
    const int wave = tid >> 6;
    const int lane = tid & 63;
    const int wr = wave >> 2;        // 0..1
    const int wc = wave & 3;         // 0..3
    const int fr = lane & 15;
    const int fs = lane >> 4;        // 0..3
    const int kswz = ((lane & 7) ^ (lane >> 3)) * 8;  // pre-swizzled global k
    const int m0 = blockIdx.y * 256;
    const int n0 = blockIdx.x * 256;

    const int kc = K / gridDim.z;
    const int kb = blockIdx.z * kc;
    C += (size_t)blockIdx.z * M * N;
    const int NT = kc >> 6;          // K-tiles (even for all our shapes)

    f32x4 acc[8][4] = {};
    b16x8 Ag[4][2], Bf[2][2], Bs2[2][2];

#define KOF(T)   (kb + ((T) < NT ? (T) : (NT - 1)) * 64)

#define STAGE_A(BUF, T, R0) { \
    const int k0_ = KOF(T); \
    _Pragma("unroll") for (int hh = 0; hh < 2; ++hh) { \
        const int rp_ = (R0) + hh * 64 + wave * 8 + (lane >> 3); \
        const int L_  = ((rp_ >> 6) & 1) * 128 + ((rp_ >> 7) & 1) * 64 + (rp_ & 63); \
        load_lds16(A + (size_t)(m0 + L_) * K + k0_ + kswz, \
                   &lds[BUF][0][((R0) + hh * 64 + wave * 8) * 64]); } }

#define STAGE_B(BUF, T, R0) { \
    const int k0_ = KOF(T); \
    _Pragma("unroll") for (int hh = 0; hh < 2; ++hh) { \
        const int rp_ = (R0) + hh * 64 + wave * 8 + (lane >> 3); \
        const int L_  = ((rp_ >> 5) & 3) * 64 + ((rp_ >> 7) & 1) * 32 + (rp_ & 31); \
        load_lds16(B + (size_t)(n0 + L_) * K + k0_ + kswz, \
                   &lds[BUF][1][((R0) + hh * 64 + wave * 8) * 64]); } }

#define LDA_G(BUF, IBASE) \
    _Pragma("unroll") for (int ii = 0; ii < 4; ++ii) { \
        const int rp_ = (IBASE) + 64 * wr + ii * 16 + fr; \
        _Pragma("unroll") for (int h = 0; h < 2; ++h) \
            Ag[ii][h] = *(const b16x8*)&lds[BUF][0][rp_ * 64 + (((h * 4 + fs) ^ (rp_ & 7)) * 8)]; }

#define LDB_G(BUF, JBASE, DST) \
    _Pragma("unroll") for (int jj = 0; jj < 2; ++jj) { \
        const int rp_ = (JBASE) + 32 * wc + jj * 16 + fr; \
        _Pragma("unroll") for (int h = 0; h < 2; ++h) \
            DST[jj][h] = *(const b16x8*)&lds[BUF][1][rp_ * 64 + (((h * 4 + fs) ^ (rp_ & 7)) * 8)]; }

#define MFMA_Q(IB, JB, BREG) \
    __builtin_amdgcn_s_setprio(1); \
    _Pragma("unroll") for (int ii = 0; ii < 4; ++ii) \
    _Pragma("unroll") for (int jj = 0; jj < 2; ++jj) \
    _Pragma("unroll") for (int h = 0; h < 2; ++h) \
        acc[(IB) + ii][(JB) + jj] = __builtin_amdgcn_mfma_f32_16x16x32_bf16( \
            Ag[ii][h], BREG[jj][h], acc[(IB) + ii][(JB) + jj], 0, 0, 0); \
    __builtin_amdgcn_s_setprio(0);

#define BAR1  { __builtin_amdgcn_s_barrier(); __builtin_amdgcn_sched_barrier(0); }
#define BAR2  { __builtin_amdgcn_s_barrier(); }
#define VMW6  { asm volatile("s_waitcnt vmcnt(6)" ::: "memory"); \
                __builtin_amdgcn_sched_barrier(0); }

    // prologue: tile0 fully into buf0 (8 loads), then A1,B1,B2 of tile1 (6).
    // vmcnt(6) -> tile0's 8 loads landed; tile1's 6 stay in flight.
    STAGE_A(0, 0, 0);   STAGE_B(0, 0, 0);   STAGE_B(0, 0, 128);  STAGE_A(0, 0, 128);
    STAGE_A(1, 1, 0);   STAGE_B(1, 1, 0);   STAGE_B(1, 1, 128);
    VMW6; BAR2;

    const int nit = NT >> 1;
    for (int it = 0; it < nit; ++it) {
        const int t1 = 2 * it + 1;
        // ph1: Q00(t0) buf0           | stage A2(t1) -> buf1
        LDA_G(0, 0); LDB_G(0, 0, Bf);
        STAGE_A(1, t1, 128);
        BAR1; MFMA_Q(0, 0, Bf); BAR2;
        // ph2: Q01(t0) (A reuse)      | stage A1(t0+2) -> buf0
        LDB_G(0, 128, Bs2);
        STAGE_A(0, t1 + 1, 0);
        BAR1; MFMA_Q(0, 2, Bs2); BAR2;
        // ph3: Q11(t0) (B2 reuse)     | stage B1(t0+2) -> buf0
        LDA_G(0, 128);
        STAGE_B(0, t1 + 1, 0);
        BAR1; MFMA_Q(4, 2, Bs2); BAR2;
        // ph4: Q10(t0) (all reuse)    | stage B2(t0+2) -> buf0 | vmcnt(6)
        STAGE_B(0, t1 + 1, 128);
        BAR1; MFMA_Q(4, 0, Bf); VMW6; BAR2;
        // ph5: Q00(t1) buf1           | stage A2(t0+2) -> buf0
        LDA_G(1, 0); LDB_G(1, 0, Bf);
        STAGE_A(0, t1 + 1, 128);
        BAR1; MFMA_Q(0, 0, Bf); BAR2;
        // ph6: Q01(t1)                | stage A1(t1+2) -> buf1
        LDB_G(1, 128, Bs2);
        STAGE_A(1, t1 + 2, 0);
        BAR1; MFMA_Q(0, 2, Bs2); BAR2;
        // ph7: Q11(t1)                | stage B1(t1+2) -> buf1
        LDA_G(1, 128);
        STAGE_B(1, t1 + 2, 0);
        BAR1; MFMA_Q(4, 2, Bs2); BAR2;
        // ph8: Q10(t1)                | stage B2(t1+2) -> buf1 | vmcnt(6)
        STAGE_B(1, t1 + 2, 128);
        BAR1; MFMA_Q(4, 0, Bf); VMW6; BAR2;
    }

    // epilogue: C/D layout col=lane&15, row=(lane>>4)*4+reg
    const int col  = lane & 15;
    const int row4 = (lane >> 4) * 4;
#pragma unroll
    for (int j = 0; j < 4; ++j) {
        const int n = n0 + wc * 64 + j * 16 + col;
        const float bj = BIAS ? bias[n] : 0.f;
#pragma unroll
        for (int i = 0; i < 8; ++i) {
#pragma unroll
            for (int r = 0; r < 4; ++r) {
                const int m = m0 + wr * 128 + i * 16 + row4 + r;
                C[(size_t)m * N + n] = acc[i][j][r] + bj;
            }
        }
    }
#undef KOF
#undef STAGE_A
#undef STAGE_B
#undef LDA_G
#undef LDB_G
#undef MFMA_Q
#undef BAR1
#undef BAR2
#undef VMW6
}

// ---------------------------------------------------------------------------
// prep_x: one pass over x producing xb (bf16, same layout) and xT (bf16,
// transposed). 64x64 tile through LDS.
// ---------------------------------------------------------------------------
__global__ __launch_bounds__(256) void prep_x(
    const float* __restrict__ in, unsigned short* __restrict__ xb,
    unsigned short* __restrict__ xT)
{
    __shared__ unsigned short tile[64][68];
    const int t  = threadIdx.x;
    const int c0 = blockIdx.x * 64;   // d
    const int r0 = blockIdx.y * 64;   // token
    const int tr = t >> 4, tc4 = (t & 15) * 4;
#pragma unroll
    for (int i = 0; i < 4; ++i) {
        const int r = tr + i * 16;
        const float4 v = *(const float4*)&in[(size_t)(r0 + r) * DDIM + c0 + tc4];
        ushort4 o;
        o.x = f2b(v.x); o.y = f2b(v.y); o.z = f2b(v.z); o.w = f2b(v.w);
        *(ushort4*)&xb[(size_t)(r0 + r) * DDIM + c0 + tc4] = o;
        tile[tc4 + 0][r] = o.x; tile[tc4 + 1][r] = o.y;
        tile[tc4 + 2][r] = o.z; tile[tc4 + 3][r] = o.w;
    }
    __syncthreads();
#pragma unroll
    for (int i = 0; i < 4; ++i) {
        const int r = tr + i * 16;
        ushort4 o;
        o.x = tile[r][tc4 + 0]; o.y = tile[r][tc4 + 1];
        o.z = tile[r][tc4 + 2]; o.w = tile[r][tc4 + 3];
        *(ushort4*)&xT[(size_t)(c0 + r) * TOKENS + r0 + tc4] = o;
    }
}

// ---------------------------------------------------------------------------
// elementwise fp32 -> bf16 cast, 8 elems/thread (phi_w only)
// ---------------------------------------------------------------------------
__global__ __launch_bounds__(256) void cast_f32_bf16(
    const float* __restrict__ in, unsigned short* __restrict__ out)
{
    const size_t i = (size_t)(blockIdx.x * 256 + threadIdx.x) * 8;
    const float4 a = *(const float4*)&in[i];
    const float4 b = *(const float4*)&in[i + 4];
    ushort4 o0, o1;
    o0.x = f2b(a.x); o0.y = f2b(a.y); o0.z = f2b(a.z); o0.w = f2b(a.w);
    o1.x = f2b(b.x); o1.y = f2b(b.y); o1.z = f2b(b.z); o1.w = f2b(b.w);
    *(ushort4*)&out[i]     = o0;
    *(ushort4*)&out[i + 4] = o1;
}

// ---------------------------------------------------------------------------
// tiled transpose bf16 -> bf16 / fp32 -> bf16: in [R,C] -> out [C,R]
// ---------------------------------------------------------------------------
template<typename TIN>
__global__ __launch_bounds__(256) void transpose_cast(
    const TIN* __restrict__ in, unsigned short* __restrict__ out, int R, int C)
{
    __shared__ unsigned short tile[64][68];
    const int t  = threadIdx.x;
    const int r0 = blockIdx.y * 64, c0 = blockIdx.x * 64;
    const int tr = t >> 4, tc4 = (t & 15) * 4;
#pragma unroll
    for (int i = 0; i < 4; ++i) {
        const int r = tr + i * 16;
        const TIN* p = in + (size_t)(r0 + r) * C + c0 + tc4;
        if constexpr (sizeof(TIN) == 4) {
            const float4 v = *(const float4*)p;
            tile[tc4 + 0][r] = f2b(v.x); tile[tc4 + 1][r] = f2b(v.y);
            tile[tc4 + 2][r] = f2b(v.z); tile[tc4 + 3][r] = f2b(v.w);
        } else {
            const ushort4 v = *(const ushort4*)p;
            tile[tc4 + 0][r] = v.x; tile[tc4 + 1][r] = v.y;
            tile[tc4 + 2][r] = v.z; tile[tc4 + 3][r] = v.w;
        }
    }
    __syncthreads();
#pragma unroll
    for (int i = 0; i < 4; ++i) {
        const int r = tr + i * 16;
        ushort4 o;
        o.x = tile[r][tc4 + 0]; o.y = tile[r][tc4 + 1];
        o.z = tile[r][tc4 + 2]; o.w = tile[r][tc4 + 3];
        *(ushort4*)&out[(size_t)(c0 + r) * R + r0 + tc4] = o;
    }
}

// ---------------------------------------------------------------------------
// Fused dispatch/combine softmax. One block per token. bf16 outputs.
// ---------------------------------------------------------------------------
__global__ __launch_bounds__(256) void softmax_dc(
    const float* __restrict__ logits,
    unsigned short* __restrict__ Db, unsigned short* __restrict__ Cb)
{
    __shared__ float ls[NEXP * 33];     // padded: index e + e/32
    __shared__ float dmax[NEXP], dinv[NEXP];
    __shared__ float cmax[PSLOT], cinv[PSLOT];
    const int tid = threadIdx.x;
    const size_t base = (size_t)blockIdx.x * NSLOTS;

#pragma unroll
    for (int i = 0; i < 8; ++i) {
        const int e = tid + i * 256;
        ls[e + (e >> 5)] = logits[base + e];
    }
    __syncthreads();

    if (tid < 64) {
        const float* r = &ls[tid * 33];
        float m = r[0];
#pragma unroll
        for (int p = 1; p < PSLOT; ++p) m = fmaxf(m, r[p]);
        float s = 0.f;
#pragma unroll
        for (int p = 0; p < PSLOT; ++p) s += __expf(r[p] - m);
        dmax[tid] = m; dinv[tid] = 1.f / s;
    } else if (tid < 96) {
        const int p = tid - 64;
        float m = ls[p];
#pragma unroll
        for (int n = 1; n < NEXP; ++n) m = fmaxf(m, ls[n * 33 + p]);
        float s = 0.f;
#pragma unroll
        for (int n = 0; n < NEXP; ++n) s += __expf(ls[n * 33 + p] - m);
        cmax[p] = m; cinv[p] = 1.f / s;
    }
    __syncthreads();

#pragma unroll
    for (int i = 0; i < 8; ++i) {
        const int e = tid + i * 256;
        const int n = e >> 5, p = e & 31;
        const float l = ls[e + n];
        Db[base + e] = f2b(__expf(l - dmax[n]) * dinv[n]);
        Cb[base + e] = f2b(__expf(l - cmax[p]) * cinv[p]);
    }
}

// ---------------------------------------------------------------------------
// split-K reduce -> clip -> LayerNorm -> tanh. One block per slot row.
// ---------------------------------------------------------------------------
__global__ __launch_bounds__(256) void reduce_ln_tanh(
    const float* __restrict__ parts, float* __restrict__ Xt)
{
    const int tid = threadIdx.x;
    const size_t off = (size_t)blockIdx.x * DDIM + tid * 4;
    __shared__ float red1[4], red2[4];

    float4 v = *(const float4*)&parts[off];
#pragma unroll
    for (int s = 1; s < KSPLIT; ++s) {
        const float4 p = *(const float4*)&parts[(size_t)s * NSLOTS * DDIM + off];
        v.x += p.x; v.y += p.y; v.z += p.z; v.w += p.w;
    }
    v.x = fminf(fmaxf(v.x, -33000.f), 65000.f);
    v.y = fminf(fmaxf(v.y, -33000.f), 65000.f);
    v.z = fminf(fmaxf(v.z, -33000.f), 65000.f);
    v.w = fminf(fmaxf(v.w, -33000.f), 65000.f);

    float s = v.x + v.y + v.z + v.w;
#pragma unroll
    for (int off2 = 32; off2 > 0; off2 >>= 1) s += __shfl_down(s, off2);
    if ((tid & 63) == 0) red1[tid >> 6] = s;
    __syncthreads();
    const float mu = (red1[0] + red1[1] + red1[2] + red1[3]) * (1.f / DDIM);

    const float dx = v.x - mu, dy = v.y - mu, dz = v.z - mu, dw = v.w - mu;
    float q = dx * dx + dy * dy + dz * dz + dw * dw;
#pragma unroll
    for (int off2 = 32; off2 > 0; off2 >>= 1) q += __shfl_down(q, off2);
    if ((tid & 63) == 0) red2[tid >> 6] = q;
    __syncthreads();
    const float var = (red2[0] + red2[1] + red2[2] + red2[3]) * (1.f / DDIM);
    const float sc = rsqrtf(var + LN_EPS);

    float4 o;
    o.x = tanhf(dx * sc); o.y = tanhf(dy * sc);
    o.z = tanhf(dz * sc); o.w = tanhf(dw * sc);
    *(float4*)&Xt[off] = o;
}

// ---------------------------------------------------------------------------
// Per-expert GEMM (fp32, HBM-bound on one-shot 256 MB read of W):
// Yt[n, 0:32, h0:h0+64] = Xt[n] (32x1024) @ W[n] (1024x1024) + b[n]
// ---------------------------------------------------------------------------
__global__ __launch_bounds__(256) void expert_gemm(
    const float* __restrict__ Xt, const float* __restrict__ W,
    const float* __restrict__ bias, float* __restrict__ Yt)
{
    const int n   = blockIdx.y;
    const int h0  = blockIdx.x * 64;
    const int tid = threadIdx.x;
    __shared__ float As[32][17];
    __shared__ float Bs[16][68];

    const int r  = tid >> 3;
    const int c8 = (tid & 7) * 8;
    float acc[8];
#pragma unroll
    for (int j = 0; j < 8; ++j) acc[j] = 0.f;

    const float* Wn = W + (size_t)n * DDIM * HDIM;
    for (int k0 = 0; k0 < DDIM; k0 += 16) {
        if (tid < 128) {
            const int row = tid >> 2, c4 = (tid & 3) * 4;
            const float4 v = *(const float4*)&Xt[(size_t)(n * 32 + row) * DDIM + k0 + c4];
            As[row][c4 + 0] = v.x; As[row][c4 + 1] = v.y;
            As[row][c4 + 2] = v.z; As[row][c4 + 3] = v.w;
        }
        {
            const int row = tid >> 4, c4 = (tid & 15) * 4;
            *(float4*)&Bs[row][c4] =
                *(const float4*)&Wn[(size_t)(k0 + row) * HDIM + h0 + c4];
        }
        __syncthreads();
#pragma unroll
        for (int kk = 0; kk < 16; ++kk) {
            const float a = As[r][kk];
            const float4 b0 = *(const float4*)&Bs[kk][c8];
            const float4 b1 = *(const float4*)&Bs[kk][c8 + 4];
            acc[0] = fmaf(a, b0.x, acc[0]); acc[1] = fmaf(a, b0.y, acc[1]);
            acc[2] = fmaf(a, b0.z, acc[2]); acc[3] = fmaf(a, b0.w, acc[3]);
            acc[4] = fmaf(a, b1.x, acc[4]); acc[5] = fmaf(a, b1.y, acc[5]);
            acc[6] = fmaf(a, b1.z, acc[6]); acc[7] = fmaf(a, b1.w, acc[7]);
        }
        __syncthreads();
    }

    float4 o0, o1;
    const float* bn = bias + (size_t)n * HDIM + h0 + c8;
    o0.x = acc[0] + bn[0]; o0.y = acc[1] + bn[1];
    o0.z = acc[2] + bn[2]; o0.w = acc[3] + bn[3];
    o1.x = acc[4] + bn[4]; o1.y = acc[5] + bn[5];
    o1.z = acc[6] + bn[6]; o1.w = acc[7] + bn[7];
    float* outp = Yt + (size_t)(n * 32 + r) * HDIM + h0 + c8;
    *(float4*)&outp[0] = o0;
    *(float4*)&outp[4] = o1;
}

// ---------------------------------------------------------------------------
extern "C" void kernel_launch(void* const* d_in, const int* in_sizes, int n_in,
                              void* d_out, int out_size, void* d_ws, size_t ws_size,
                              hipStream_t stream)
{
    const float* x        = (const float*)d_in[0];  // [16384, 1024]
    const float* phi_w    = (const float*)d_in[1];  // [2048, 1024]
    const float* phi_b    = (const float*)d_in[2];  // [2048]
    const float* expert_w = (const float*)d_in[3];  // [64, 1024, 1024]
    const float* expert_b = (const float*)d_in[4];  // [64, 1024]
    float* out = (float*)d_out;                     // [16384, 1024]

    char* ws = (char*)d_ws;
    const size_t MB = 1u << 20;
    unsigned short* xb     = (unsigned short*)(ws);              // 32 MB
    unsigned short* xT     = (unsigned short*)(ws +  32 * MB);   // 32 MB
    unsigned short* pwb    = (unsigned short*)(ws +  64 * MB);   //  4 MB
    float*          logits = (float*)(ws +  68 * MB);            // 128 MB
    unsigned short* Db     = (unsigned short*)(ws + 196 * MB);   // 64 MB
    unsigned short* Cb     = (unsigned short*)(ws + 260 * MB);   // 64 MB
    unsigned short* DbT    = (unsigned short*)(ws + 324 * MB);   // 64 MB
    float*          parts  = (float*)(ws + 388 * MB);            // 64 MB
    float*          Xt     = (float*)(ws + 452 * MB);            //  8 MB
    float*          Yt     = (float*)(ws + 460 * MB);            //  8 MB
    unsigned short* YtT    = (unsigned short*)(ws + 468 * MB);   //  4 MB

    // 0. prep: x -> xb + xT (one read), phi_w -> bf16
    prep_x<<<dim3(DDIM / 64, TOKENS / 64), 256, 0, stream>>>(x, xb, xT);
    cast_f32_bf16<<<NSLOTS * DDIM / (256 * 8), 256, 0, stream>>>(phi_w, pwb);

    // 1. logits = x @ phi_w^T + phi_b   (8-phase 256^2 MFMA, 512 blocks)
    gemm_nt_256<true><<<dim3(NSLOTS / 256, TOKENS / 256), 512, 0, stream>>>(
        xb, pwb, phi_b, logits, TOKENS, NSLOTS, DDIM);

    // 2. dispatch/combine softmax -> bf16 D, C
    softmax_dc<<<TOKENS, 256, 0, stream>>>(logits, Db, Cb);

    // 3a. DbT = D^T bf16 [2048, 16384]
    transpose_cast<unsigned short><<<dim3(NSLOTS / 64, TOKENS / 64), 256, 0, stream>>>(
        Db, DbT, TOKENS, NSLOTS);

    // 3b. X_tilde partials = D^T @ x, split-K 8 (256 blocks = 1/CU)
    gemm_nt_256<false>
        <<<dim3(DDIM / 256, NSLOTS / 256, KSPLIT), 512, 0, stream>>>(
            DbT, xT, nullptr, parts, NSLOTS, DDIM, TOKENS);

    // 4. reduce splits -> clip -> LN -> tanh
    reduce_ln_tanh<<<NSLOTS, 256, 0, stream>>>(parts, Xt);

    // 5. per-expert linear (fp32)
    expert_gemm<<<dim3(HDIM / 64, NEXP), 256, 0, stream>>>(
        Xt, expert_w, expert_b, Yt);

    // 5b. YtT = Yt^T bf16 [1024, 2048]
    transpose_cast<float><<<dim3(HDIM / 64, NSLOTS / 64), 256, 0, stream>>>(
        Yt, YtT, NSLOTS, HDIM);

    // 6. Y = C @ Y_tilde   (8-phase 256^2 MFMA, 256 blocks)
    gemm_nt_256<false><<<dim3(HDIM / 256, TOKENS / 256), 512, 0, stream>>>(
        Cb, YtT, nullptr, out, TOKENS, HDIM, NSLOTS);
}